// Round 8
// baseline (30527.670 us; speedup 1.0000x reference)
//
#include <hip/hip_runtime.h>
#include <hip/hip_bf16.h>

typedef unsigned short u16;
typedef unsigned int u32;
typedef __attribute__((ext_vector_type(4))) float f32x4;
typedef __attribute__((ext_vector_type(8))) short bf16x8;

#define DEVI static __device__ __forceinline__

DEVI u16 f2bf(float f) {
  u32 u = __builtin_bit_cast(u32, f);
  u += 0x7fffu + ((u >> 16) & 1u);
  return (u16)(u >> 16);
}

DEVI void gload_lds16(const void* g, void* l) {
  __builtin_amdgcn_global_load_lds(
      (const __attribute__((address_space(1))) u32*)g,
      (__attribute__((address_space(3))) u32*)l, 16, 0, 0);
}

template<int N> DEVI void wait_vm() {
  if constexpr (N == 0)       asm volatile("s_waitcnt vmcnt(0)" ::: "memory");
  else if constexpr (N == 4)  asm volatile("s_waitcnt vmcnt(4)" ::: "memory");
  else if constexpr (N == 9)  asm volatile("s_waitcnt vmcnt(9)" ::: "memory");
  else                        asm volatile("s_waitcnt vmcnt(0)" ::: "memory");
}
DEVI void lgkm_barrier() {
  asm volatile("s_waitcnt lgkmcnt(0)\n\ts_barrier" ::: "memory");
}

struct Aregs { f32x4 v0, v1; uint4 h; };

// ---------------------------------------------------------------------------
// r7-proven small-K GEMM (used for P1, P3): C[64 x BN] = A @ Bt^T.
// B per-wave slice via global_load_lds, DEPTH=1; A reg->LDS swizzled dbuf.
// EPI0: bf16 transposed store outh[n][M]+m.
// ---------------------------------------------------------------------------
template<int BM, int BN, int BK, bool AF32, int DEPTH>
DEVI void gemm_phase(const void* __restrict__ Ap, const u16* __restrict__ Bt,
                     const int Kfull, const int klen, const int M,
                     u16* __restrict__ outh, char* smem,
                     const int m0, const int tid)
{
  constexpr int TN = BN / 8;
  constexpr int MF = BM / 16, NF = TN / 16, KK = BK / 32;
  constexpr int ABYTES = BM * BK * 2;
  constexpr int SLICE = TN * BK * 2;
  constexpr int LB = SLICE / 1024;
  constexpr int LA = AF32 ? 2 : 1;
  constexpr int NB = DEPTH + 1;
  constexpr int VMW = DEPTH * (LA + LB);
  constexpr int CPR = BK / 8;
  static_assert(BM * BK == 4096, "one 16B A chunk per thread");

  const int w = tid >> 6, l = tid & 63;
  const int l15 = l & 15, l4 = l >> 4;
  const int NT = klen / BK;

  auto off = [&](int row, int q) -> int {
    if constexpr (BK == 64) return row * 128 + ((q ^ (row & 7)) << 4);
    else                    return row * 64 + ((q ^ ((row >> 1) & 3)) << 4);
  };

  const int ar = tid / CPR, ac = tid % CPR;
  const int apos = off(ar, ac);
  const size_t Abase = (size_t)(m0 + ar) * Kfull + (size_t)ac * 8;

  char* const bslice = smem + 2 * ABYTES + w * SLICE;

  f32x4 acc[MF][NF];
#pragma unroll
  for (int i = 0; i < MF; ++i)
#pragma unroll
    for (int j = 0; j < NF; ++j) acc[i][j] = (f32x4){0.f, 0.f, 0.f, 0.f};

  Aregs R0, R1;

  auto issueA = [&](Aregs& R, int t) {
    if constexpr (AF32) {
      const float* p = (const float*)Ap + Abase + (size_t)t * BK;
      R.v0 = *(const f32x4*)p;
      R.v1 = *(const f32x4*)(p + 4);
    } else {
      const u16* p = (const u16*)Ap + Abase + (size_t)t * BK;
      R.h = *(const uint4*)p;
    }
  };
  auto writeA = [&](int nb, Aregs& R) {
    uint4 pk;
    if constexpr (AF32) {
      pk.x = (u32)f2bf(R.v0[0]) | ((u32)f2bf(R.v0[1]) << 16);
      pk.y = (u32)f2bf(R.v0[2]) | ((u32)f2bf(R.v0[3]) << 16);
      pk.z = (u32)f2bf(R.v1[0]) | ((u32)f2bf(R.v1[1]) << 16);
      pk.w = (u32)f2bf(R.v1[2]) | ((u32)f2bf(R.v1[3]) << 16);
    } else {
      pk = R.h;
    }
    *(uint4*)(smem + nb * ABYTES + apos) = pk;
  };
  auto issueB = [&](int nb, int t) {
    const char* bsrc = (const char*)Bt +
                       (size_t)(w * TN) * ((size_t)Kfull * 2) +
                       (size_t)(t * BK) * 2;
    char* bd = bslice + nb * (8 * SLICE);
#pragma unroll
    for (int i = 0; i < LB; ++i) {
      const int p = i * 1024 + l * 16;
      const int nl = (BK == 64) ? (p >> 7) : (p >> 6);
      const int chp = (p & (BK * 2 - 1)) >> 4;
      const int q = (BK == 64) ? (chp ^ (nl & 7)) : (chp ^ ((nl >> 1) & 3));
      gload_lds16(bsrc + (size_t)nl * ((size_t)Kfull * 2) + q * 16,
                  bd + i * 1024);
    }
  };
  auto compute = [&](int ab, int bb) {
    const char* A = smem + ab * ABYTES;
    const char* Bs = bslice + bb * (8 * SLICE);
#pragma unroll
    for (int kk = 0; kk < KK; ++kk) {
      bf16x8 af[MF];
      uint4 bfr[NF];
#pragma unroll
      for (int mi = 0; mi < MF; ++mi)
        af[mi] = *(const bf16x8*)(A + off(mi * 16 + l15, kk * 4 + l4));
#pragma unroll
      for (int ni = 0; ni < NF; ++ni)
        bfr[ni] = *(const uint4*)(Bs + off(ni * 16 + l15, kk * 4 + l4));
      __builtin_amdgcn_s_setprio(1);
#pragma unroll
      for (int mi = 0; mi < MF; ++mi)
#pragma unroll
        for (int ni = 0; ni < NF; ++ni)
          acc[mi][ni] = __builtin_amdgcn_mfma_f32_16x16x32_bf16(
              af[mi], __builtin_bit_cast(bf16x8, bfr[ni]), acc[mi][ni],
              0, 0, 0);
      __builtin_amdgcn_s_setprio(0);
    }
  };

  issueB(0, 0);
  issueA(R0, 0);
  issueA(R1, NT > 1 ? 1 : 0);
  if constexpr (DEPTH == 2) issueB(1, NT > 1 ? 1 : 0);
  writeA(0, R0);
  lgkm_barrier();

  int bc = 0, bi = DEPTH % NB;
  int t2 = 0;

#define SUBSTEP(RI, RW, ABUF)                                                \
  {                                                                          \
    const int tA = (t2 + 2 < NT) ? t2 + 2 : NT - 1;                          \
    const int tB = (t2 + DEPTH < NT) ? t2 + DEPTH : NT - 1;                  \
    issueA(RI, tA);                                                          \
    issueB(bi, tB);                                                          \
    wait_vm<VMW>();                                                          \
    compute(ABUF, bc);                                                       \
    writeA(ABUF ^ 1, RW);                                                    \
    lgkm_barrier();                                                          \
    bc = (bc + 1 == NB) ? 0 : bc + 1;                                        \
    bi = (bi + 1 == NB) ? 0 : bi + 1;                                        \
    ++t2;                                                                    \
  }

  for (int it = 0; it < NT / 2; ++it) {
    SUBSTEP(R0, R1, 0);
    SUBSTEP(R1, R0, 1);
  }
#undef SUBSTEP

  wait_vm<0>();

  const int mrow0 = m0 + l4 * 4;
#pragma unroll
  for (int ni = 0; ni < NF; ++ni) {
    const int n = w * TN + ni * 16 + l15;
#pragma unroll
    for (int mi = 0; mi < MF; ++mi) {
      const int m = mrow0 + mi * 16;
      ushort4 o;
      o.x = f2bf(acc[mi][ni][0]);
      o.y = f2bf(acc[mi][ni][1]);
      o.z = f2bf(acc[mi][ni][2]);
      o.w = f2bf(acc[mi][ni][3]);
      *(ushort4*)(outh + (size_t)n * M + m) = o;
    }
  }
}

template<int BN, bool AF32>
__global__ __launch_bounds__(512, 2)
void gemm64_k(const void* Ap, const u16* Bt, const int K, const int M,
              u16* outh)
{
  __shared__ char smem[2 * 8192 + 2 * 8 * (BN / 8) * 64 * 2];
  const int m0 = ((blockIdx.x & 7) * 32 + (blockIdx.x >> 3)) * 64;
  gemm_phase<64, BN, 64, AF32, 1>(Ap, Bt, K, K, M, outh, smem, m0,
                                  threadIdx.x);
}

// ---------------------------------------------------------------------------
// NEW P2/P4 GEMM: C[128 x BN] partial = a[m0.., k0..] @ Bt[BN][K]^T.
// 512 thr = 8 waves (1x8). B: REGISTERS (no LDS), 2 named sets, issue->use
// = 2 K-steps. A: fp32->bf16, 2 named reg sets -> swizzled 16KB LDS dbuf.
// KSPLIT=KS partial k-chunks; KS==4 pins kc per XCD (B slice L2-resident).
// 16KB LDS + ~220 VGPR -> 2 blocks/CU (latency overlap across blocks).
// REPS: idempotent re-execution (rocprof probe); deterministic.
// ---------------------------------------------------------------------------
template<int BN, int KS, int REPS>
__global__ __launch_bounds__(512, 4)
void gemm_breg(const float* __restrict__ Ap, const u16* __restrict__ Bt,
               const int Kfull, const int M, float* __restrict__ outP)
{
  constexpr int BM = 128, BK = 32;
  constexpr int TN = BN / 8;           // 64 | 16
  constexpr int MF = BM / 16;          // 8
  constexpr int NF = TN / 16;          // 4 | 1
  constexpr int ABYTES = BM * BK * 2;  // 8 KiB
  __shared__ char smem[2 * ABYTES];

  const int tid = threadIdx.x;
  const int w = tid >> 6, l = tid & 63;
  const int l15 = l & 15, l4 = l >> 4;

  int m0, kc;
  if constexpr (KS == 4) {             // grid 512: 128 m-tiles x 4 kc
    const int xcd = blockIdx.x & 7;
    kc = xcd & 3;                      // kc uniform per XCD
    m0 = ((int)(blockIdx.x >> 3) + (xcd >> 2) * 64) * BM;
  } else {                             // grid 256: 128 m-tiles x 2 kc
    kc = blockIdx.x & 1;
    const int q = blockIdx.x >> 1;
    m0 = ((q & 3) * 32 + (q >> 2)) * BM;
  }
  const int klen = Kfull / KS;
  const int k0 = kc * klen;
  const int NT = klen / BK;            // 128 | 256 (even)

  const int ar = tid >> 2, ac = tid & 3;
  const int apos = ar * 64 + ((ac ^ ((ar >> 1) & 3)) << 4);
  const float* Aba = Ap + (size_t)(m0 + ar) * Kfull + k0 + ac * 8;
  const u16* Bba = Bt + (size_t)(w * TN + l15) * Kfull + k0 + l4 * 8;

  for (int rep = 0; rep < REPS; ++rep) {
    f32x4 acc[MF][NF];
#pragma unroll
    for (int i = 0; i < MF; ++i)
#pragma unroll
      for (int j = 0; j < NF; ++j) acc[i][j] = (f32x4){0.f, 0.f, 0.f, 0.f};

    f32x4 A0a, A0b, A1a, A1b;          // named reg sets (no runtime index)
    uint4 B0[NF], B1[NF];

    auto loadA0 = [&](int t) {
      const float* p = Aba + (size_t)t * BK;
      A0a = *(const f32x4*)p; A0b = *(const f32x4*)(p + 4);
    };
    auto loadA1 = [&](int t) {
      const float* p = Aba + (size_t)t * BK;
      A1a = *(const f32x4*)p; A1b = *(const f32x4*)(p + 4);
    };
    auto storeA = [&](int nb, const f32x4& va, const f32x4& vb) {
      uint4 pk;
      pk.x = (u32)f2bf(va[0]) | ((u32)f2bf(va[1]) << 16);
      pk.y = (u32)f2bf(va[2]) | ((u32)f2bf(va[3]) << 16);
      pk.z = (u32)f2bf(vb[0]) | ((u32)f2bf(vb[1]) << 16);
      pk.w = (u32)f2bf(vb[2]) | ((u32)f2bf(vb[3]) << 16);
      *(uint4*)(smem + nb * ABYTES + apos) = pk;
    };
    auto loadB = [&](uint4 (&B)[NF], int t) {
#pragma unroll
      for (int ni = 0; ni < NF; ++ni)
        B[ni] = *(const uint4*)(Bba + (size_t)(ni * 16) * Kfull +
                                (size_t)t * BK);
    };
    auto compute = [&](int ab, uint4 (&B)[NF]) {
      const char* A = smem + ab * ABYTES;
      bf16x8 af[MF];
#pragma unroll
      for (int mi = 0; mi < MF; ++mi) {
        const int row = mi * 16 + l15;
        af[mi] = *(const bf16x8*)(A + row * 64 +
                                  ((l4 ^ ((row >> 1) & 3)) << 4));
      }
      __builtin_amdgcn_s_setprio(1);
#pragma unroll
      for (int mi = 0; mi < MF; ++mi)
#pragma unroll
        for (int ni = 0; ni < NF; ++ni)
          acc[mi][ni] = __builtin_amdgcn_mfma_f32_16x16x32_bf16(
              af[mi], __builtin_bit_cast(bf16x8, B[ni]), acc[mi][ni],
              0, 0, 0);
      __builtin_amdgcn_s_setprio(0);
    };

    // prologue: A(0) oldest so storeA's reg-wait leaves B0/B1/A1 in flight
    loadA0(0);
    loadB(B0, 0);
    loadB(B1, NT > 1 ? 1 : 0);
    loadA1(NT > 1 ? 1 : 0);
    storeA(0, A0a, A0b);
    lgkm_barrier();

    for (int it = 0; it < NT / 2; ++it) {
      const int t = 2 * it;
      {
        const int tp = (t + 2 < NT) ? t + 2 : NT - 1;
        loadA0(tp);                 // A(t+2)
        compute(0, B0);             // uses B(t) (issued at t-2)
        loadB(B0, tp);              // B(t+2) after MFMAs consumed B0
        storeA(1, A1a, A1b);        // A(t+1) -> buf1 (reg-wait counted)
        lgkm_barrier();
      }
      {
        const int tp = (t + 3 < NT) ? t + 3 : NT - 1;
        loadA1(tp);
        compute(1, B1);
        loadB(B1, tp);
        storeA(0, A0a, A0b);
        lgkm_barrier();
      }
    }

    float* Pout = outP + (size_t)kc * ((size_t)M * BN);
    const int mrow0 = m0 + l4 * 4;
#pragma unroll
    for (int ni = 0; ni < NF; ++ni) {
      const int n = w * TN + ni * 16 + l15;
#pragma unroll
      for (int mi = 0; mi < MF; ++mi)
#pragma unroll
        for (int r = 0; r < 4; ++r)
          Pout[(size_t)(mrow0 + mi * 16 + r) * BN + n] = acc[mi][ni][r];
    }
    if (REPS > 1) {
      asm volatile("s_waitcnt vmcnt(0)" ::: "memory");
      __syncthreads();
    }
  }
}

// ---------------------------------------------------------------------------
__global__ __launch_bounds__(256)
void bn1_cast_k(const float* __restrict__ x, const float* __restrict__ g,
                const float* __restrict__ be, const float* __restrict__ rm,
                const float* __restrict__ rv, u16* __restrict__ out)
{
  const size_t i8 = ((size_t)blockIdx.x * 256 + threadIdx.x) * 8;
  const f32x4 v0 = *(const f32x4*)(x + i8);
  const f32x4 v1 = *(const f32x4*)(x + i8 + 4);
  const int f0 = (int)(i8 & 511);
  u16 u[8];
#pragma unroll
  for (int e = 0; e < 8; ++e) {
    const int f = f0 + e;
    const float sc = g[f] * rsqrtf(rv[f] + 1e-5f);
    const float v = (e < 4) ? v0[e] : v1[e - 4];
    u[e] = f2bf((v - rm[f]) * sc + be[f]);
  }
  uint4 o;
  o.x = (u32)u[0] | ((u32)u[1] << 16);
  o.y = (u32)u[2] | ((u32)u[3] << 16);
  o.z = (u32)u[4] | ((u32)u[5] << 16);
  o.w = (u32)u[6] | ((u32)u[7] << 16);
  *(uint4*)(out + i8) = o;
}

__global__ __launch_bounds__(256)
void tcvt_k(const float* __restrict__ in, u16* __restrict__ out, int rowlen)
{
  const int o = blockIdx.x * 256 + threadIdx.x;
  out[o] = f2bf(in[(size_t)(o & 511) * rowlen + (o >> 9)]);
}

template<int KS>
__global__ __launch_bounds__(256)
void comb_bn_k(const float* __restrict__ P, const float* __restrict__ b1,
               const float* __restrict__ g2, const float* __restrict__ be2,
               const float* __restrict__ rm2, const float* __restrict__ rv2,
               float* __restrict__ out)
{
  const size_t i4 = ((size_t)blockIdx.x * 256 + threadIdx.x) * 4;
  f32x4 s = *(const f32x4*)(P + i4);
#pragma unroll
  for (int c = 1; c < KS; ++c) {
    const f32x4 p = *(const f32x4*)(P + (size_t)c * (16384ull * 512) + i4);
#pragma unroll
    for (int e = 0; e < 4; ++e) s[e] += p[e];
  }
  const int f0 = (int)(i4 & 511);
  f32x4 o;
#pragma unroll
  for (int e = 0; e < 4; ++e) {
    const int f = f0 + e;
    float v = fmaxf(s[e] + b1[f], 0.f);
    const float sc = g2[f] * rsqrtf(rv2[f] + 1e-5f);
    o[e] = v * sc + (be2[f] - rm2[f] * sc);
  }
  *(f32x4*)(out + i4) = o;
}

template<int KS>
__global__ __launch_bounds__(256)
void comb_k(const float* __restrict__ P, const float* __restrict__ b2,
            float* __restrict__ out)
{
  const size_t i4 = ((size_t)blockIdx.x * 256 + threadIdx.x) * 4;
  f32x4 s = *(const f32x4*)(P + i4);
#pragma unroll
  for (int c = 1; c < KS; ++c) {
    const f32x4 p = *(const f32x4*)(P + (size_t)c * (16384ull * 128) + i4);
#pragma unroll
    for (int e = 0; e < 4; ++e) s[e] += p[e];
  }
  const int f0 = (int)(i4 & 127);
  f32x4 o;
#pragma unroll
  for (int e = 0; e < 4; ++e) o[e] = s[e] + b2[f0 + e];
  *(f32x4*)(out + i4) = o;
}

// ---------------------------------------------------------------------------
extern "C" void kernel_launch(void* const* d_in, const int* in_sizes, int n_in,
                              void* d_out, int out_size, void* d_ws, size_t ws_size,
                              hipStream_t stream)
{
  const float* x   = (const float*)d_in[0];
  const float* a   = (const float*)d_in[1];
  const float* w1  = (const float*)d_in[2];
  const float* b1  = (const float*)d_in[3];
  const float* w2  = (const float*)d_in[4];
  const float* b2  = (const float*)d_in[5];
  const float* g1  = (const float*)d_in[6];
  const float* be1 = (const float*)d_in[7];
  const float* rm1 = (const float*)d_in[8];
  const float* rv1 = (const float*)d_in[9];
  const float* g2  = (const float*)d_in[10];
  const float* be2 = (const float*)d_in[11];
  const float* rm2 = (const float*)d_in[12];
  const float* rv2 = (const float*)d_in[13];

  constexpr int N = 16384, F = 512, H = 512, C = 128;
  float* x1 = (float*)d_out;                      // [N][C]
  float* x2 = (float*)d_out + (size_t)N * C;      // [N][H]

  char* wsp = (char*)d_ws;
  u16* xb  = (u16*)wsp;  wsp += (size_t)N * F * 2;        // 16 MiB
  u16* t_t = (u16*)wsp;  wsp += (size_t)H * N * 2;        // 16 MiB
  u16* z_t = (u16*)wsp;  wsp += (size_t)C * N * 2;        //  4 MiB
  u16* w1t = (u16*)wsp;  wsp += (size_t)H * F * 2;
  u16* w2t = (u16*)wsp;  wsp += (size_t)C * H * 2;
  float* Pp = (float*)wsp;                                // partials (shared)
  const size_t used = (size_t)(wsp - (char*)d_ws);
  const bool big = ws_size >= used + 4ull * N * H * 4;    // 4 fp32 partials

  bn1_cast_k<<<(N * F / 8) / 256, 256, 0, stream>>>(x, g1, be1, rm1, rv1, xb);
  tcvt_k<<<(F * H) / 256, 256, 0, stream>>>(w1, w1t, H);
  tcvt_k<<<(H * C) / 256, 256, 0, stream>>>(w2, w2t, C);

  // P1: t = xb @ w1t -> t_t[h][n]
  gemm64_k<512, false><<<256, 512, 0, stream>>>(xb, w1t, F, N, t_t);

  // P2: a @ t partials (REPS=5 probe on the KS=4 path)
  if (big) {
    gemm_breg<512, 4, 5><<<512, 512, 0, stream>>>(a, t_t, N, N, Pp);
    comb_bn_k<4><<<(N * H / 4) / 256, 256, 0, stream>>>(Pp, b1, g2, be2,
                                                        rm2, rv2, x2);
  } else {
    gemm_breg<512, 2, 1><<<256, 512, 0, stream>>>(a, t_t, N, N, Pp);
    comb_bn_k<2><<<(N * H / 4) / 256, 256, 0, stream>>>(Pp, b1, g2, be2,
                                                        rm2, rv2, x2);
  }

  // P3: z = x2 @ w2t -> z_t[c][n]
  gemm64_k<128, true><<<256, 512, 0, stream>>>(x2, w2t, H, N, z_t);

  // P4: a @ z partials (aliases Pp; C2 already consumed it)
  if (big) {
    gemm_breg<128, 4, 5><<<512, 512, 0, stream>>>(a, z_t, N, N, Pp);
    comb_k<4><<<(N * C / 4) / 256, 256, 0, stream>>>(Pp, b2, x1);
  } else {
    gemm_breg<128, 2, 1><<<256, 512, 0, stream>>>(a, z_t, N, N, Pp);
    comb_k<2><<<(N * C / 4) / 256, 256, 0, stream>>>(Pp, b2, x1);
  }
}

// Round 9
// 700.513 us; speedup vs baseline: 43.5790x; 43.5790x over previous
//
#include <hip/hip_runtime.h>
#include <hip/hip_bf16.h>

typedef unsigned short u16;
typedef unsigned int u32;
typedef __attribute__((ext_vector_type(4))) float f32x4;
typedef __attribute__((ext_vector_type(8))) short bf16x8;

#define DEVI static __device__ __forceinline__

DEVI u16 f2bf(float f) {
  u32 u = __builtin_bit_cast(u32, f);
  u += 0x7fffu + ((u >> 16) & 1u);
  return (u16)(u >> 16);
}

DEVI void gload_lds16(const void* g, void* l) {
  __builtin_amdgcn_global_load_lds(
      (const __attribute__((address_space(1))) u32*)g,
      (__attribute__((address_space(3))) u32*)l, 16, 0, 0);
}

template<int N> DEVI void wait_vm() {
  if constexpr (N == 0)      asm volatile("s_waitcnt vmcnt(0)" ::: "memory");
  else if constexpr (N == 5) asm volatile("s_waitcnt vmcnt(5)" ::: "memory");
  else if constexpr (N == 6) asm volatile("s_waitcnt vmcnt(6)" ::: "memory");
  else if constexpr (N == 8) asm volatile("s_waitcnt vmcnt(8)" ::: "memory");
  else                       asm volatile("s_waitcnt vmcnt(0)" ::: "memory");
}
DEVI void lgkm_barrier() {
  asm volatile("s_waitcnt lgkmcnt(0)\n\ts_barrier" ::: "memory");
}

struct Aregs { f32x4 v0, v1; uint4 h; };

// ---------------------------------------------------------------------------
// C[64 x BN_T] = A[m0.., k0..k0+klen] @ Bt[n0+.., k]^T (bf16 Bt).
// 512 thr = 8 waves (1x8 over the BN_T columns). BM=64, BK=64.
// A: reg-staged (fp32->bf16 cvt or bf16), 2 named reg sets, XOR-swizzled
// ds_write into 16KB LDS dbuf. B: per-wave slice via global_load_lds
// (inverse-swizzled global source), DEPTH deep into DEPTH+1 bufs.
// Counted waits: VMW = DEPTH*(LA+LB); one lgkmcnt(0)+s_barrier per step;
// vmcnt(0) drain before epilogue. NT even at all call sites (8/256/128).
// NSPL: split BN_FULL into NSPL n-tiles (independent blocks, no combine).
// KSPL: split K into KSPL chunks -> fp32 partials (EPI2).
// EPI 0: bf16 transposed store outh[n][M]+m.
// EPI 1: outf[m][BN_FULL] = bn2(relu(acc + e0)) fused (e1..e4 = g2,be2,rm2,rv2)
// EPI 2: fp32 partial -> outf + kc*M*BN_FULL.
// launch_bounds(512,4): cap 128 VGPR -> 2 blocks/CU (verified headroom:
// worst acc = 4x2x4 = 32 VGPR).
// ---------------------------------------------------------------------------
template<int BN_FULL, int BN_T, bool AF32, int EPI, int NSPL, int KSPL,
         int DEPTH>
__global__ __launch_bounds__(512, 4)
void gk(const void* __restrict__ Ap, const u16* __restrict__ Bt,
        const int Kfull, const int M, float* __restrict__ outf,
        u16* __restrict__ outh,
        const float* __restrict__ e0, const float* __restrict__ e1,
        const float* __restrict__ e2, const float* __restrict__ e3,
        const float* __restrict__ e4)
{
  constexpr int BM = 64, BK = 64;
  constexpr int TN = BN_T / 8;
  constexpr int MF = 4, NF = TN / 16;
  constexpr int ABYTES = BM * BK * 2;      // 8 KiB
  constexpr int SLICE = TN * BK * 2;       // 4 KiB | 2 KiB
  constexpr int LB = SLICE / 1024;
  constexpr int LA = AF32 ? 2 : 1;
  constexpr int NB = DEPTH + 1;
  constexpr int VMW = DEPTH * (LA + LB);
  constexpr int SPL = NSPL * KSPL;

  __shared__ char smem[2 * ABYTES + NB * 8 * SLICE];

  const int tid = threadIdx.x;
  const int w = tid >> 6, l = tid & 63;
  const int l15 = l & 15, l4 = l >> 4;

  // XCD-contiguous decode: same-XCD blocks cover contiguous m (L2 A+B reuse)
  const int G8 = gridDim.x >> 3;
  const int q = (blockIdx.x & 7) * G8 + (blockIdx.x >> 3);
  const int sub = q % SPL;
  const int m0 = (q / SPL) * BM;
  const int nh = (NSPL == 2) ? sub : 0;
  const int kc = (KSPL == 2) ? sub : 0;
  const int n0 = nh * BN_T;
  const int klen = Kfull / KSPL;
  const int k0 = kc * klen;
  const int NT = klen / BK;

  auto off = [&](int row, int chq) -> int {
    return row * 128 + ((chq ^ (row & 7)) << 4);
  };

  const int ar = tid >> 3, ac = tid & 7;
  const int apos = off(ar, ac);
  const size_t Abase = (size_t)(m0 + ar) * Kfull + k0 + (size_t)ac * 8;

  char* const bslice = smem + 2 * ABYTES + w * SLICE;

  f32x4 acc[MF][NF];
#pragma unroll
  for (int i = 0; i < MF; ++i)
#pragma unroll
    for (int j = 0; j < NF; ++j) acc[i][j] = (f32x4){0.f, 0.f, 0.f, 0.f};

  Aregs R0, R1;

  auto issueA = [&](Aregs& R, int t) {
    if constexpr (AF32) {
      const float* p = (const float*)Ap + Abase + (size_t)t * BK;
      R.v0 = *(const f32x4*)p;
      R.v1 = *(const f32x4*)(p + 4);
    } else {
      const u16* p = (const u16*)Ap + Abase + (size_t)t * BK;
      R.h = *(const uint4*)p;
    }
  };
  auto writeA = [&](int nb, Aregs& R) {
    uint4 pk;
    if constexpr (AF32) {
      pk.x = (u32)f2bf(R.v0[0]) | ((u32)f2bf(R.v0[1]) << 16);
      pk.y = (u32)f2bf(R.v0[2]) | ((u32)f2bf(R.v0[3]) << 16);
      pk.z = (u32)f2bf(R.v1[0]) | ((u32)f2bf(R.v1[1]) << 16);
      pk.w = (u32)f2bf(R.v1[2]) | ((u32)f2bf(R.v1[3]) << 16);
    } else {
      pk = R.h;
    }
    *(uint4*)(smem + nb * ABYTES + apos) = pk;
  };
  auto issueB = [&](int nb, int t) {
    const char* bsrc = (const char*)Bt +
                       ((size_t)(n0 + w * TN) * Kfull + k0 +
                        (size_t)t * BK) * 2;
    char* bd = bslice + nb * (8 * SLICE);
#pragma unroll
    for (int i = 0; i < LB; ++i) {
      const int p = i * 1024 + l * 16;
      const int nl = p >> 7;                    // row within wave slice
      const int chq = ((p & 127) >> 4) ^ (nl & 7);
      gload_lds16(bsrc + (size_t)nl * ((size_t)Kfull * 2) + chq * 16,
                  bd + i * 1024);
    }
  };
  auto compute = [&](int ab, int bb) {
    const char* A = smem + ab * ABYTES;
    const char* Bs = bslice + bb * (8 * SLICE);
#pragma unroll
    for (int kk = 0; kk < 2; ++kk) {
      bf16x8 af[MF];
      uint4 bfr[NF];
#pragma unroll
      for (int mi = 0; mi < MF; ++mi)
        af[mi] = *(const bf16x8*)(A + off(mi * 16 + l15, kk * 4 + l4));
#pragma unroll
      for (int ni = 0; ni < NF; ++ni)
        bfr[ni] = *(const uint4*)(Bs + off(ni * 16 + l15, kk * 4 + l4));
      __builtin_amdgcn_s_setprio(1);
#pragma unroll
      for (int mi = 0; mi < MF; ++mi)
#pragma unroll
        for (int ni = 0; ni < NF; ++ni)
          acc[mi][ni] = __builtin_amdgcn_mfma_f32_16x16x32_bf16(
              af[mi], __builtin_bit_cast(bf16x8, bfr[ni]), acc[mi][ni],
              0, 0, 0);
      __builtin_amdgcn_s_setprio(0);
    }
  };

  // prologue
  issueB(0, 0);
  issueA(R0, 0);
  issueA(R1, NT > 1 ? 1 : 0);
  if constexpr (DEPTH == 2) issueB(1, NT > 1 ? 1 : 0);
  writeA(0, R0);
  lgkm_barrier();

  int bc = 0, bi = DEPTH % NB;
  int t2 = 0;

#define SUBSTEP(RI, RW, ABUF)                                                \
  {                                                                          \
    const int tA = (t2 + 2 < NT) ? t2 + 2 : NT - 1;                          \
    const int tB = (t2 + DEPTH < NT) ? t2 + DEPTH : NT - 1;                  \
    issueA(RI, tA);                                                          \
    issueB(bi, tB);                                                          \
    wait_vm<VMW>();                                                          \
    compute(ABUF, bc);                                                       \
    writeA(ABUF ^ 1, RW);                                                    \
    lgkm_barrier();                                                          \
    bc = (bc + 1 == NB) ? 0 : bc + 1;                                        \
    bi = (bi + 1 == NB) ? 0 : bi + 1;                                        \
    ++t2;                                                                    \
  }

  for (int it = 0; it < NT / 2; ++it) {
    SUBSTEP(R0, R1, 0);
    SUBSTEP(R1, R0, 1);
  }
#undef SUBSTEP

  wait_vm<0>();   // drain clamped-tail gload_lds

  const int mrow0 = m0 + l4 * 4;
#pragma unroll
  for (int ni = 0; ni < NF; ++ni) {
    const int n = n0 + w * TN + ni * 16 + l15;
    if constexpr (EPI == 0) {
#pragma unroll
      for (int mi = 0; mi < MF; ++mi) {
        const int m = mrow0 + mi * 16;
        ushort4 o;
        o.x = f2bf(acc[mi][ni][0]);
        o.y = f2bf(acc[mi][ni][1]);
        o.z = f2bf(acc[mi][ni][2]);
        o.w = f2bf(acc[mi][ni][3]);
        *(ushort4*)(outh + (size_t)n * M + m) = o;
      }
    } else if constexpr (EPI == 1) {
      const float b1v = e0[n];
      const float sc = e1[n] * rsqrtf(e4[n] + 1e-5f);
      const float sh = e2[n] - e3[n] * sc;
#pragma unroll
      for (int mi = 0; mi < MF; ++mi)
#pragma unroll
        for (int r = 0; r < 4; ++r) {
          const float s = fmaxf(acc[mi][ni][r] + b1v, 0.f);
          outf[(size_t)(mrow0 + mi * 16 + r) * BN_FULL + n] = s * sc + sh;
        }
    } else {
      float* Pout = outf + (size_t)kc * ((size_t)M * BN_FULL);
#pragma unroll
      for (int mi = 0; mi < MF; ++mi)
#pragma unroll
        for (int r = 0; r < 4; ++r)
          Pout[(size_t)(mrow0 + mi * 16 + r) * BN_FULL + n] = acc[mi][ni][r];
    }
  }
}

// ---------------------------------------------------------------------------
__global__ __launch_bounds__(256)
void bn1_cast_k(const float* __restrict__ x, const float* __restrict__ g,
                const float* __restrict__ be, const float* __restrict__ rm,
                const float* __restrict__ rv, u16* __restrict__ out)
{
  const size_t i8 = ((size_t)blockIdx.x * 256 + threadIdx.x) * 8;
  const f32x4 v0 = *(const f32x4*)(x + i8);
  const f32x4 v1 = *(const f32x4*)(x + i8 + 4);
  const int f0 = (int)(i8 & 511);
  u16 u[8];
#pragma unroll
  for (int e = 0; e < 8; ++e) {
    const int f = f0 + e;
    const float sc = g[f] * rsqrtf(rv[f] + 1e-5f);
    const float v = (e < 4) ? v0[e] : v1[e - 4];
    u[e] = f2bf((v - rm[f]) * sc + be[f]);
  }
  uint4 o;
  o.x = (u32)u[0] | ((u32)u[1] << 16);
  o.y = (u32)u[2] | ((u32)u[3] << 16);
  o.z = (u32)u[4] | ((u32)u[5] << 16);
  o.w = (u32)u[6] | ((u32)u[7] << 16);
  *(uint4*)(out + i8) = o;
}

__global__ __launch_bounds__(256)
void tcvt_k(const float* __restrict__ in, u16* __restrict__ out, int rowlen)
{
  const int o = blockIdx.x * 256 + threadIdx.x;
  out[o] = f2bf(in[(size_t)(o & 511) * rowlen + (o >> 9)]);
}

// x1 = P0 + P1 + b2 ; row length 128
__global__ __launch_bounds__(256)
void comb_k(const float* __restrict__ P, const float* __restrict__ b2,
            float* __restrict__ out)
{
  const size_t i4 = ((size_t)blockIdx.x * 256 + threadIdx.x) * 4;
  const f32x4 p0 = *(const f32x4*)(P + i4);
  const f32x4 p1 = *(const f32x4*)(P + (size_t)16384 * 128 + i4);
  const int f0 = (int)(i4 & 127);
  f32x4 o;
#pragma unroll
  for (int e = 0; e < 4; ++e) o[e] = p0[e] + p1[e] + b2[f0 + e];
  *(f32x4*)(out + i4) = o;
}

// ---------------------------------------------------------------------------
extern "C" void kernel_launch(void* const* d_in, const int* in_sizes, int n_in,
                              void* d_out, int out_size, void* d_ws, size_t ws_size,
                              hipStream_t stream)
{
  const float* x   = (const float*)d_in[0];
  const float* a   = (const float*)d_in[1];
  const float* w1  = (const float*)d_in[2];
  const float* b1  = (const float*)d_in[3];
  const float* w2  = (const float*)d_in[4];
  const float* b2  = (const float*)d_in[5];
  const float* g1  = (const float*)d_in[6];
  const float* be1 = (const float*)d_in[7];
  const float* rm1 = (const float*)d_in[8];
  const float* rv1 = (const float*)d_in[9];
  const float* g2  = (const float*)d_in[10];
  const float* be2 = (const float*)d_in[11];
  const float* rm2 = (const float*)d_in[12];
  const float* rv2 = (const float*)d_in[13];

  constexpr int N = 16384, F = 512, H = 512, C = 128;
  float* x1 = (float*)d_out;                      // [N][C]
  float* x2 = (float*)d_out + (size_t)N * C;      // [N][H]

  char* wsp = (char*)d_ws;
  u16* xb  = (u16*)wsp;  wsp += (size_t)N * F * 2;   // bn1(x) bf16
  u16* t_t = (u16*)wsp;  wsp += (size_t)H * N * 2;   // (bn1x@w1)^T
  u16* z_t = (u16*)wsp;  wsp += (size_t)C * N * 2;   // (x2@w2)^T
  u16* w1t = (u16*)wsp;  wsp += (size_t)H * F * 2;   // w1^T
  u16* w2t = (u16*)wsp;  wsp += (size_t)C * H * 2;   // w2^T
  float* Pp = (float*)wsp;                           // P4 partials (2x 8 MiB)

  bn1_cast_k<<<(N * F / 8) / 256, 256, 0, stream>>>(x, g1, be1, rm1, rv1, xb);
  tcvt_k<<<(F * H) / 256, 256, 0, stream>>>(w1, w1t, H);
  tcvt_k<<<(H * C) / 256, 256, 0, stream>>>(w2, w2t, C);

  // P1: t = xb @ w1t -> t_t[h][n]   (N-split 2, grid 512, 2 blocks/CU)
  gk<512, 256, false, 0, 2, 1, 1><<<512, 512, 0, stream>>>(
      xb, w1t, F, N, nullptr, t_t, nullptr, nullptr, nullptr, nullptr, nullptr);

  // P2: x2 = bn2(relu(a @ t + b1)) direct  (N-split 2, grid 512, 2/CU)
  gk<512, 256, true, 1, 2, 1, 1><<<512, 512, 0, stream>>>(
      a, t_t, N, N, x2, nullptr, b1, g2, be2, rm2, rv2);

  // P3: z = x2 @ w2t -> z_t[c][n]   (grid 256)
  gk<128, 128, true, 0, 1, 1, 2><<<256, 512, 0, stream>>>(
      x2, w2t, H, N, nullptr, z_t, nullptr, nullptr, nullptr, nullptr, nullptr);

  // P4: a @ z partials (K-split 2, grid 512, 2/CU) -> Pp
  gk<128, 128, true, 2, 1, 2, 2><<<512, 512, 0, stream>>>(
      a, z_t, N, N, Pp, nullptr, nullptr, nullptr, nullptr, nullptr, nullptr);

  // C4: x1 = Pp0 + Pp1 + b2
  comb_k<<<(N * C / 4) / 256, 256, 0, stream>>>(Pp, b2, x1);
}